// Round 3
// baseline (1638.818 us; speedup 1.0000x reference)
//
#include <hip/hip_runtime.h>
#include <math.h>

// ---------------------------------------------------------------------------
// Pipeline:
//  k_zero2    : zero degree counters
//  k_deg      : in-degree count per dst (both graphs), int atomics
//  k_scan     : single-block exclusive scan -> CSR row offsets, cursors, dinv
//  k_scatter  : fill CSR src lists (atomic cursor)
//  k_cnn      : per-(node,t) conv1d(16,k40,s88)+relu + linear 80->40+relu
//               -> seq[4][N][41] (t<4, incl y) and feats[N][0..39] (t=4)
//  k_gru      : 64-node blocks, weights+h in LDS, 4 GRU steps -> feats[N][40..103]
//  k_hw       : hs_g[n] = dinv_g[n] * (feats[n] @ Wg)  for both GCNs
//  k_agg (x2) : pull aggregation over CSR + bias + relu + fused MLP dot -> out
// ---------------------------------------------------------------------------

__global__ __launch_bounds__(256) void k_cnn(
    const float* __restrict__ x,       // [R][395]
    const float* __restrict__ conv_w,  // [16][40]
    const float* __restrict__ conv_b,  // [16]
    const float* __restrict__ lin_w,   // [40][80]
    const float* __restrict__ lin_b,   // [40]
    float* __restrict__ seq,           // [4][N][41]
    float* __restrict__ feats,         // [N][104]
    int nrows, int nnodes)
{
    __shared__ __align__(16) float s_sig[32][5][44];
    __shared__ __align__(16) float s_c[32][84];
    __shared__ __align__(16) float s_cw[16][44];
    __shared__ __align__(16) float s_lw[40][84];
    __shared__ float s_cb[16];
    __shared__ float s_lb[40];

    const int tid = threadIdx.x;
    const int r0  = blockIdx.x * 32;

    for (int i = tid; i < 640;  i += 256) s_cw[i/40][i%40] = conv_w[i];
    for (int i = tid; i < 3200; i += 256) s_lw[i/80][i%80] = lin_w[i];
    if (tid < 16) s_cb[tid] = conv_b[tid];
    if (tid >= 64 && tid < 104) s_lb[tid-64] = lin_b[tid-64];

    // stage the 5 conv windows per row (coalesced 160B bursts)
    const int wv = tid >> 6, ln = tid & 63;
    for (int c = wv; c < 160; c += 4) {
        int row = c / 5, p = c - row*5;
        int gr = r0 + row; if (gr >= nrows) gr = nrows - 1;
        if (ln < 40) s_sig[row][p][ln] = x[gr*395 + 3 + 88*p + ln];
    }
    // y channel -> seq[..][40]
    if (tid < 32) {
        int gr = r0 + tid;
        if (gr < nrows) {
            float y = x[gr*395 + 2];
            int node = gr / 5, t = gr - node*5;
            if (t < 4) seq[(t*nnodes + node)*41 + 40] = y;
        }
    }
    __syncthreads();

    // conv: tid = row*8 + cg, channels {2cg, 2cg+1}, 5 positions
    {
        const int row = tid >> 3, cg = tid & 7;
        float acc[2][5];
        #pragma unroll
        for (int cc = 0; cc < 2; ++cc) {
            float b = s_cb[2*cg+cc];
            #pragma unroll
            for (int p = 0; p < 5; ++p) acc[cc][p] = b;
        }
        #pragma unroll
        for (int k4 = 0; k4 < 40; k4 += 4) {
            float4 sv[5];
            #pragma unroll
            for (int p = 0; p < 5; ++p) sv[p] = *(const float4*)&s_sig[row][p][k4];
            #pragma unroll
            for (int cc = 0; cc < 2; ++cc) {
                float4 w4 = *(const float4*)&s_cw[2*cg+cc][k4];
                #pragma unroll
                for (int p = 0; p < 5; ++p)
                    acc[cc][p] += w4.x*sv[p].x + w4.y*sv[p].y + w4.z*sv[p].z + w4.w*sv[p].w;
            }
        }
        #pragma unroll
        for (int cc = 0; cc < 2; ++cc)
            #pragma unroll
            for (int p = 0; p < 5; ++p)
                s_c[row][(2*cg+cc)*5 + p] = fmaxf(acc[cc][p], 0.0f);
    }
    __syncthreads();

    // linear 80->40: tid = row*8 + jg, 1 row, outputs {5jg..5jg+4}  (jg<8 -> 40 outputs)
    {
        const int row = tid >> 3, jg = tid & 7;
        float acc[5];
        #pragma unroll
        for (int jj = 0; jj < 5; ++jj) acc[jj] = s_lb[5*jg+jj];
        #pragma unroll
        for (int i4 = 0; i4 < 80; i4 += 4) {
            float4 c0 = *(const float4*)&s_c[row][i4];
            #pragma unroll
            for (int jj = 0; jj < 5; ++jj) {
                float4 w4 = *(const float4*)&s_lw[5*jg+jj][i4];
                acc[jj] += w4.x*c0.x + w4.y*c0.y + w4.z*c0.z + w4.w*c0.w;
            }
        }
        int gr = r0 + row;
        if (gr < nrows) {
            int node = gr / 5, t = gr - node*5;
            #pragma unroll
            for (int jj = 0; jj < 5; ++jj) {
                float v = fmaxf(acc[jj], 0.0f);
                if (t < 4) seq[(t*nnodes + node)*41 + 5*jg+jj] = v;
                else       feats[node*104 + 5*jg+jj] = v;
            }
        }
    }
}

__global__ __launch_bounds__(256) void k_gru(
    const float* __restrict__ seq,    // [4][N][41]
    const float* __restrict__ w_ih,   // [192][41]
    const float* __restrict__ w_hh,   // [192][64]
    const float* __restrict__ b_ih,
    const float* __restrict__ b_hh,
    float* __restrict__ feats,        // [N][104]
    int nnodes)
{
    __shared__ __align__(16) float s_wi[41][194];  // transposed [k][gate]
    __shared__ __align__(16) float s_wh[64][194];
    __shared__ __align__(16) float s_h[64][68];    // [hidden j][node]
    __shared__ __align__(16) float s_x[41][68];    // [k][node]
    __shared__ float s_bi[192], s_bh[192];

    const int tid  = threadIdx.x;
    const int nblk = blockIdx.x * 64;

    for (int i = tid; i < 192*41; i += 256) { int g = i/41, k = i - g*41; s_wi[k][g] = w_ih[i]; }
    for (int i = tid; i < 192*64; i += 256) { int g = i>>6, k = i&63;     s_wh[k][g] = w_hh[i]; }
    if (tid < 192) { s_bi[tid] = b_ih[tid]; s_bh[tid] = b_hh[tid]; }
    for (int i = tid; i < 64*64; i += 256) s_h[i>>6][i&63] = 0.0f;

    const int jg = tid & 31, ngp = tid >> 5;
    const int j0 = 2*jg, n0 = 8*ngp;     // thread tile: 2 hidden x 8 nodes

    float hreg[2][8];
    #pragma unroll
    for (int a = 0; a < 2; ++a)
        #pragma unroll
        for (int b = 0; b < 8; ++b) hreg[a][b] = 0.0f;

    for (int t = 0; t < 4; ++t) {
        __syncthreads();
        for (int i = tid; i < 64*41; i += 256) {
            int n = i/41, k = i - n*41;
            int node = nblk + n; if (node >= nnodes) node = nnodes - 1;
            s_x[k][n] = seq[(t*nnodes + node)*41 + k];
        }
        __syncthreads();

        float ar[2][8], az[2][8], ani[2][8], anh[2][8];
        #pragma unroll
        for (int a = 0; a < 2; ++a)
            #pragma unroll
            for (int b = 0; b < 8; ++b) { ar[a][b]=0.f; az[a][b]=0.f; ani[a][b]=0.f; anh[a][b]=0.f; }

        for (int k = 0; k < 41; ++k) {
            float4 xa = *(const float4*)&s_x[k][n0];
            float4 xb = *(const float4*)&s_x[k][n0+4];
            float xv[8] = {xa.x,xa.y,xa.z,xa.w,xb.x,xb.y,xb.z,xb.w};
            float2 wr = *(const float2*)&s_wi[k][j0];
            float2 wz = *(const float2*)&s_wi[k][64+j0];
            float2 wn = *(const float2*)&s_wi[k][128+j0];
            #pragma unroll
            for (int nn = 0; nn < 8; ++nn) {
                ar[0][nn] += wr.x*xv[nn]; ar[1][nn] += wr.y*xv[nn];
                az[0][nn] += wz.x*xv[nn]; az[1][nn] += wz.y*xv[nn];
                ani[0][nn]+= wn.x*xv[nn]; ani[1][nn]+= wn.y*xv[nn];
            }
        }
        for (int k = 0; k < 64; ++k) {
            float4 ha = *(const float4*)&s_h[k][n0];
            float4 hb = *(const float4*)&s_h[k][n0+4];
            float hv[8] = {ha.x,ha.y,ha.z,ha.w,hb.x,hb.y,hb.z,hb.w};
            float2 wr = *(const float2*)&s_wh[k][j0];
            float2 wz = *(const float2*)&s_wh[k][64+j0];
            float2 wn = *(const float2*)&s_wh[k][128+j0];
            #pragma unroll
            for (int nn = 0; nn < 8; ++nn) {
                ar[0][nn] += wr.x*hv[nn]; ar[1][nn] += wr.y*hv[nn];
                az[0][nn] += wz.x*hv[nn]; az[1][nn] += wz.y*hv[nn];
                anh[0][nn]+= wn.x*hv[nn]; anh[1][nn]+= wn.y*hv[nn];
            }
        }

        #pragma unroll
        for (int jj = 0; jj < 2; ++jj) {
            int j = j0 + jj;
            float br  = s_bi[j]     + s_bh[j];
            float bz  = s_bi[64+j]  + s_bh[64+j];
            float bin = s_bi[128+j], bhn = s_bh[128+j];
            #pragma unroll
            for (int nn = 0; nn < 8; ++nn) {
                float r = 1.0f/(1.0f + expf(-(ar[jj][nn] + br)));
                float z = 1.0f/(1.0f + expf(-(az[jj][nn] + bz)));
                float g = tanhf(ani[jj][nn] + bin + r*(anh[jj][nn] + bhn));
                hreg[jj][nn] = (1.0f - z)*g + z*hreg[jj][nn];
            }
        }
        __syncthreads();   // all reads of old h done
        #pragma unroll
        for (int jj = 0; jj < 2; ++jj) {
            *(float4*)&s_h[j0+jj][n0]   = make_float4(hreg[jj][0],hreg[jj][1],hreg[jj][2],hreg[jj][3]);
            *(float4*)&s_h[j0+jj][n0+4] = make_float4(hreg[jj][4],hreg[jj][5],hreg[jj][6],hreg[jj][7]);
        }
    }

    #pragma unroll
    for (int jj = 0; jj < 2; ++jj)
        #pragma unroll
        for (int nn = 0; nn < 8; ++nn) {
            int node = nblk + n0 + nn;
            if (node < nnodes) feats[node*104 + 40 + j0 + jj] = hreg[jj][nn];
        }
}

__global__ __launch_bounds__(256) void k_hw(
    const float* __restrict__ feats,   // [N][104]
    const float* __restrict__ w1,      // [104][40]
    const float* __restrict__ w2,      // [104][40]
    const float* __restrict__ dinv1,
    const float* __restrict__ dinv2,
    float* __restrict__ hs1,           // [N][40]
    float* __restrict__ hs2,
    int nnodes)
{
    __shared__ __align__(16) float s_f[128][108];
    __shared__ __align__(16) float s_w[80][108];
    __shared__ float s_d[2][128];

    const int tid  = threadIdx.x;
    const int nblk = blockIdx.x * 128;

    for (int i = tid; i < 128*104; i += 256) {
        int n = i/104, k = i - n*104;
        int node = nblk + n; if (node >= nnodes) node = nnodes - 1;
        s_f[n][k] = feats[node*104 + k];
    }
    for (int i = tid; i < 80*104; i += 256) {
        int o = i/104, k = i - o*104;
        s_w[o][k] = (o < 40) ? w1[k*40 + o] : w2[k*40 + (o-40)];
    }
    if (tid < 128) {
        int node = nblk + tid; if (node >= nnodes) node = nnodes - 1;
        s_d[0][tid] = dinv1[node]; s_d[1][tid] = dinv2[node];
    }
    __syncthreads();

    const int og = tid & 7, ngp = tid >> 3;   // tile: 4 nodes x 10 outputs
    const int o0 = 10*og, n0 = 4*ngp;
    float acc[4][10];
    #pragma unroll
    for (int a = 0; a < 4; ++a)
        #pragma unroll
        for (int b = 0; b < 10; ++b) acc[a][b] = 0.0f;

    for (int k4 = 0; k4 < 104; k4 += 4) {
        float4 f[4];
        #pragma unroll
        for (int nn = 0; nn < 4; ++nn) f[nn] = *(const float4*)&s_f[n0+nn][k4];
        #pragma unroll
        for (int oo = 0; oo < 10; ++oo) {
            float4 w4 = *(const float4*)&s_w[o0+oo][k4];
            #pragma unroll
            for (int nn = 0; nn < 4; ++nn)
                acc[nn][oo] += w4.x*f[nn].x + w4.y*f[nn].y + w4.z*f[nn].z + w4.w*f[nn].w;
        }
    }
    #pragma unroll
    for (int nn = 0; nn < 4; ++nn) {
        int node = nblk + n0 + nn;
        if (node >= nnodes) continue;
        #pragma unroll
        for (int oo = 0; oo < 10; ++oo) {
            int o = o0 + oo;
            if (o < 40) hs1[node*40 + o]      = s_d[0][n0+nn] * acc[nn][oo];
            else        hs2[node*40 + (o-40)] = s_d[1][n0+nn] * acc[nn][oo];
        }
    }
}

__global__ void k_zero2(int* a, int* b, int n) {
    int i = blockIdx.x*256 + threadIdx.x;
    if (i < n) { a[i] = 0; b[i] = 0; }
}

__global__ void k_deg(const int* __restrict__ d1, const int* __restrict__ d2,
                      int* c1, int* c2, int E) {
    int i = blockIdx.x*256 + threadIdx.x;
    if (i < E) { atomicAdd(&c1[d1[i]], 1); atomicAdd(&c2[d2[i]], 1); }
}

__global__ __launch_bounds__(1024) void k_scan(
    const int* __restrict__ cnt, int* __restrict__ roff, int* __restrict__ cur,
    float* __restrict__ dinv, int n)
{
    __shared__ int sp[1024];
    int t = threadIdx.x;
    int C = (n + 1023) >> 10;
    int i0 = t*C, i1 = min(i0 + C, n);
    int s = 0;
    for (int i = i0; i < i1; ++i) s += cnt[i];
    sp[t] = s;
    __syncthreads();
    for (int off = 1; off < 1024; off <<= 1) {
        int v = (t >= off) ? sp[t-off] : 0;
        __syncthreads();
        sp[t] += v;
        __syncthreads();
    }
    int run = sp[t] - s;
    for (int i = i0; i < i1; ++i) {
        int c = cnt[i];
        roff[i] = run; cur[i] = run;
        dinv[i] = rsqrtf((float)(c + 1));
        run += c;
    }
    if (t == 1023) roff[n] = sp[1023];
}

__global__ void k_scatter(const int* __restrict__ e1, const int* __restrict__ e2,
                          int* cur1, int* cur2, int* csr1, int* csr2, int E) {
    int i = blockIdx.x*256 + threadIdx.x;
    if (i < E) {
        int s = e1[i], d = e1[E+i];
        csr1[atomicAdd(&cur1[d], 1)] = s;
        s = e2[i]; d = e2[E+i];
        csr2[atomicAdd(&cur2[d], 1)] = s;
    }
}

__global__ __launch_bounds__(256) void k_agg(
    const float* __restrict__ hs, const int* __restrict__ csr,
    const int* __restrict__ roff, const float* __restrict__ dinv,
    const float* __restrict__ bias, const float* __restrict__ mw,
    const float* __restrict__ mlp_b, float* __restrict__ out,
    int n, int accumulate)
{
    int wv = threadIdx.x >> 6, lane = threadIdx.x & 63;
    int d = blockIdx.x*4 + wv;
    if (d >= n) return;
    int beg = roff[d], end = roff[d+1];
    int fc = lane < 40 ? lane : 0;
    float acc = 0.0f;
    int snext = (beg < end) ? csr[beg] : 0;
    for (int e = beg; e < end; ++e) {
        int s = snext;
        if (e + 1 < end) snext = csr[e+1];
        acc += hs[s*40 + fc];
    }
    float v = dinv[d]*(hs[d*40 + fc] + acc) + bias[fc];
    v = fmaxf(v, 0.0f) * mw[fc];
    if (lane >= 40) v = 0.0f;
    #pragma unroll
    for (int off = 32; off > 0; off >>= 1) v += __shfl_down(v, off);
    if (lane == 0)
        out[d] = accumulate ? (out[d] + v) : (mlp_b[0] + v);
}

extern "C" void kernel_launch(void* const* d_in, const int* in_sizes, int n_in,
                              void* d_out, int out_size, void* d_ws, size_t ws_size,
                              hipStream_t stream)
{
    const float* x      = (const float*)d_in[0];
    const int*   ei1    = (const int*)d_in[1];
    const int*   ei2    = (const int*)d_in[2];
    const float* conv_w = (const float*)d_in[3];
    const float* conv_b = (const float*)d_in[4];
    const float* lin_w  = (const float*)d_in[5];
    const float* lin_b  = (const float*)d_in[6];
    const float* w_ih   = (const float*)d_in[7];
    const float* w_hh   = (const float*)d_in[8];
    const float* b_ih   = (const float*)d_in[9];
    const float* b_hh   = (const float*)d_in[10];
    const float* g1w    = (const float*)d_in[11];
    const float* g1b    = (const float*)d_in[12];
    const float* g2w    = (const float*)d_in[13];
    const float* g2b    = (const float*)d_in[14];
    const float* mw     = (const float*)d_in[15];
    const float* mb     = (const float*)d_in[16];

    const int N = in_sizes[0] / (5*395);
    const int E = in_sizes[1] / 2;
    const int R = N*5;
    float* out = (float*)d_out;

    char* wp = (char*)d_ws;
    auto alloc = [&](size_t bytes) {
        char* p = wp; wp += (bytes + 255) & ~(size_t)255; return p;
    };
    float* seq   = (float*)alloc((size_t)4*N*41*4);
    float* feats = (float*)alloc((size_t)N*104*4);
    float* hs1   = (float*)alloc((size_t)N*40*4);
    float* hs2   = (float*)alloc((size_t)N*40*4);
    int*   csr1  = (int*)alloc((size_t)E*4);
    int*   csr2  = (int*)alloc((size_t)E*4);
    int*   cnt1  = (int*)alloc((size_t)N*4);
    int*   cnt2  = (int*)alloc((size_t)N*4);
    int*   roff1 = (int*)alloc((size_t)(N+1)*4);
    int*   roff2 = (int*)alloc((size_t)(N+1)*4);
    int*   cur1  = (int*)alloc((size_t)N*4);
    int*   cur2  = (int*)alloc((size_t)N*4);
    float* dinv1 = (float*)alloc((size_t)N*4);
    float* dinv2 = (float*)alloc((size_t)N*4);
    if ((size_t)(wp - (char*)d_ws) > ws_size) return;  // workspace too small

    hipLaunchKernelGGL(k_zero2,  dim3((N+255)/256), dim3(256), 0, stream, cnt1, cnt2, N);
    hipLaunchKernelGGL(k_deg,    dim3((E+255)/256), dim3(256), 0, stream, ei1+E, ei2+E, cnt1, cnt2, E);
    hipLaunchKernelGGL(k_scan,   dim3(1), dim3(1024), 0, stream, cnt1, roff1, cur1, dinv1, N);
    hipLaunchKernelGGL(k_scan,   dim3(1), dim3(1024), 0, stream, cnt2, roff2, cur2, dinv2, N);
    hipLaunchKernelGGL(k_scatter,dim3((E+255)/256), dim3(256), 0, stream, ei1, ei2, cur1, cur2, csr1, csr2, E);
    hipLaunchKernelGGL(k_cnn,    dim3((R+31)/32), dim3(256), 0, stream, x, conv_w, conv_b, lin_w, lin_b, seq, feats, R, N);
    hipLaunchKernelGGL(k_gru,    dim3((N+63)/64), dim3(256), 0, stream, seq, w_ih, w_hh, b_ih, b_hh, feats, N);
    hipLaunchKernelGGL(k_hw,     dim3((N+127)/128), dim3(256), 0, stream, feats, g1w, g2w, dinv1, dinv2, hs1, hs2, N);
    hipLaunchKernelGGL(k_agg,    dim3((N+3)/4), dim3(256), 0, stream, hs1, csr1, roff1, dinv1, g1b, mw,    mb, out, N, 0);
    hipLaunchKernelGGL(k_agg,    dim3((N+3)/4), dim3(256), 0, stream, hs2, csr2, roff2, dinv2, g2b, mw+40, mb, out, N, 1);
}

// Round 4
// 1225.993 us; speedup vs baseline: 1.3367x; 1.3367x over previous
//
#include <hip/hip_runtime.h>
#include <math.h>

// ---------------------------------------------------------------------------
// Pipeline:
//  k_zero2    : zero degree counters
//  k_deg      : in-degree count per dst (both graphs), int atomics
//  k_scan     : single-block exclusive scan -> CSR row offsets, cursors, dinv
//  k_scatter  : fill CSR src lists (atomic cursor)
//  k_cnn      : per-(node,t) conv1d(16,k40,s88)+relu + linear 80->40+relu
//               -> seq[4][N][41] (t<4, incl y) and feats[N][0..39] (t=4)
//               512 thr / 64 rows, reg-staged loads, s_c aliased over s_sig
//  k_gru      : 128-node blocks, 512 thr, weights+h in LDS, T14 x-prefetch
//  k_hw       : hs_g[n] = dinv_g[n] * (feats[n] @ Wg)  for both GCNs
//  k_agg (x2) : pull aggregation over CSR + bias + relu + fused MLP dot -> out
// ---------------------------------------------------------------------------

__global__ __launch_bounds__(512) void k_cnn(
    const float* __restrict__ x,       // [R][395]
    const float* __restrict__ conv_w,  // [16][40]
    const float* __restrict__ conv_b,  // [16]
    const float* __restrict__ lin_w,   // [40][80]
    const float* __restrict__ lin_b,   // [40]
    float* __restrict__ seq,           // [4][N][41]
    float* __restrict__ feats,         // [N][104]
    int nrows, int nnodes)
{
    // smem: first holds signal windows [64][200]; after conv it is reused
    // (sync-separated) as conv-output c [64][84].
    __shared__ __align__(16) float smem[64 * 200];   // 51.2 KB
    __shared__ __align__(16) float s_cw[16][44];     // 2.8 KB (pad 44: 2-way)
    __shared__ __align__(16) float s_lw[40][84];     // 13.4 KB (pad 84: conflict-free)
    __shared__ float s_cb[16];
    __shared__ float s_lb[40];

    const int tid = threadIdx.x;
    const int r0  = blockIdx.x * 64;

    // ---- issue all 25 independent signal loads first (MLP) ----
    float sg[25];
    #pragma unroll
    for (int it = 0; it < 25; ++it) {
        int i = tid + it * 512;          // i < 12800 = 64 rows * 200
        int row = i / 200, e = i - row * 200;
        int p = e / 40, kk = e - p * 40;
        int gr = r0 + row; if (gr >= nrows) gr = nrows - 1;
        sg[it] = x[(size_t)gr * 395 + 3 + 88 * p + kk];
    }

    // ---- weights into LDS (overlaps with loads above) ----
    for (int i = tid; i < 640;  i += 512) s_cw[i / 40][i % 40] = conv_w[i];
    for (int i = tid; i < 3200; i += 512) s_lw[i / 80][i % 80] = lin_w[i];
    if (tid < 16) s_cb[tid] = conv_b[tid];
    if (tid >= 64 && tid < 104) s_lb[tid - 64] = lin_b[tid - 64];

    // ---- y channel -> seq[..][40] ----
    if (tid < 64) {
        int gr = r0 + tid;
        if (gr < nrows) {
            float y = x[(size_t)gr * 395 + 2];
            int node = gr / 5, t = gr - node * 5;
            if (t < 4) seq[(t * nnodes + node) * 41 + 40] = y;
        }
    }

    // ---- write staged signal to LDS ----
    #pragma unroll
    for (int it = 0; it < 25; ++it) {
        int i = tid + it * 512;
        int row = i / 200, e = i - row * 200;
        smem[row * 200 + e] = sg[it];
    }
    __syncthreads();

    // ---- conv: tid = row*8 + cg, channels {2cg,2cg+1}, 5 positions ----
    const int row = tid >> 3, cg = tid & 7;
    float creg[2][5];
    {
        float acc[2][5];
        #pragma unroll
        for (int cc = 0; cc < 2; ++cc) {
            float b = s_cb[2 * cg + cc];
            #pragma unroll
            for (int p = 0; p < 5; ++p) acc[cc][p] = b;
        }
        #pragma unroll
        for (int k4 = 0; k4 < 40; k4 += 4) {
            float4 sv[5];
            #pragma unroll
            for (int p = 0; p < 5; ++p)
                sv[p] = *(const float4*)&smem[row * 200 + p * 40 + k4];
            #pragma unroll
            for (int cc = 0; cc < 2; ++cc) {
                float4 w4 = *(const float4*)&s_cw[2 * cg + cc][k4];
                #pragma unroll
                for (int p = 0; p < 5; ++p)
                    acc[cc][p] += w4.x * sv[p].x + w4.y * sv[p].y + w4.z * sv[p].z + w4.w * sv[p].w;
            }
        }
        #pragma unroll
        for (int cc = 0; cc < 2; ++cc)
            #pragma unroll
            for (int p = 0; p < 5; ++p) creg[cc][p] = fmaxf(acc[cc][p], 0.0f);
    }
    __syncthreads();   // all signal reads done -> smem reusable as c[64][84]

    #pragma unroll
    for (int cc = 0; cc < 2; ++cc)
        #pragma unroll
        for (int p = 0; p < 5; ++p)
            smem[row * 84 + (2 * cg + cc) * 5 + p] = creg[cc][p];
    __syncthreads();

    // ---- linear 80->40: tid = row*8 + jg, outputs {5jg..5jg+4} ----
    {
        const int jg = tid & 7;
        float acc[5];
        #pragma unroll
        for (int jj = 0; jj < 5; ++jj) acc[jj] = s_lb[5 * jg + jj];
        #pragma unroll
        for (int i4 = 0; i4 < 80; i4 += 4) {
            float4 c0 = *(const float4*)&smem[row * 84 + i4];
            #pragma unroll
            for (int jj = 0; jj < 5; ++jj) {
                float4 w4 = *(const float4*)&s_lw[5 * jg + jj][i4];
                acc[jj] += w4.x * c0.x + w4.y * c0.y + w4.z * c0.z + w4.w * c0.w;
            }
        }
        int gr = r0 + row;
        if (gr < nrows) {
            int node = gr / 5, t = gr - node * 5;
            #pragma unroll
            for (int jj = 0; jj < 5; ++jj) {
                float v = fmaxf(acc[jj], 0.0f);
                if (t < 4) seq[(t * nnodes + node) * 41 + 5 * jg + jj] = v;
                else       feats[node * 104 + 5 * jg + jj] = v;
            }
        }
    }
}

__global__ __launch_bounds__(512) void k_gru(
    const float* __restrict__ seq,    // [4][N][41]
    const float* __restrict__ w_ih,   // [192][41]
    const float* __restrict__ w_hh,   // [192][64]
    const float* __restrict__ b_ih,
    const float* __restrict__ b_hh,
    float* __restrict__ feats,        // [N][104]
    int nnodes)
{
    __shared__ __align__(16) float s_wi[41][192];  // transposed [k][gate]
    __shared__ __align__(16) float s_wh[64][192];
    __shared__ __align__(16) float s_h[64][132];   // [hidden j][node]
    __shared__ __align__(16) float s_x[41][132];   // [k][node]
    __shared__ float s_bi[192], s_bh[192];

    const int tid  = threadIdx.x;
    const int nblk = blockIdx.x * 128;

    // prefetch t=0 x-tile into regs (issued first, consumed after weights)
    float xr[11];
    #pragma unroll
    for (int r = 0; r < 11; ++r) {
        int i = tid + r * 512;                 // i < 5248 = 128*41
        if (i < 5248) {
            int nl = i / 41, k = i - nl * 41;
            int node = nblk + nl; if (node >= nnodes) node = nnodes - 1;
            xr[r] = seq[(size_t)(0 * nnodes + node) * 41 + k];
        }
    }

    for (int i = tid; i < 192 * 41; i += 512) { int g = i / 41, k = i - g * 41; s_wi[k][g] = w_ih[i]; }
    for (int i = tid; i < 192 * 64; i += 512) { int g = i >> 6,  k = i & 63;    s_wh[k][g] = w_hh[i]; }
    if (tid < 192) { s_bi[tid] = b_ih[tid]; s_bh[tid] = b_hh[tid]; }
    for (int i = tid; i < 64 * 132; i += 512) ((float*)s_h)[i] = 0.0f;

    // write t=0 x-tile
    #pragma unroll
    for (int r = 0; r < 11; ++r) {
        int i = tid + r * 512;
        if (i < 5248) { int nl = i / 41, k = i - nl * 41; s_x[k][nl] = xr[r]; }
    }
    __syncthreads();

    const int jg = tid & 31, ngp = tid >> 5;
    const int j0 = 2 * jg, n0 = 8 * ngp;     // thread tile: 2 hidden x 8 nodes

    float hreg[2][8];
    #pragma unroll
    for (int a = 0; a < 2; ++a)
        #pragma unroll
        for (int b = 0; b < 8; ++b) hreg[a][b] = 0.0f;

    for (int t = 0; t < 4; ++t) {
        // T14: issue next step's x loads before compute; write after sync
        if (t < 3) {
            #pragma unroll
            for (int r = 0; r < 11; ++r) {
                int i = tid + r * 512;
                if (i < 5248) {
                    int nl = i / 41, k = i - nl * 41;
                    int node = nblk + nl; if (node >= nnodes) node = nnodes - 1;
                    xr[r] = seq[(size_t)((t + 1) * nnodes + node) * 41 + k];
                }
            }
        }

        float ar[2][8], az[2][8], ani[2][8], anh[2][8];
        #pragma unroll
        for (int a = 0; a < 2; ++a)
            #pragma unroll
            for (int b = 0; b < 8; ++b) { ar[a][b]=0.f; az[a][b]=0.f; ani[a][b]=0.f; anh[a][b]=0.f; }

        for (int k = 0; k < 41; ++k) {
            float4 xa = *(const float4*)&s_x[k][n0];
            float4 xb = *(const float4*)&s_x[k][n0 + 4];
            float xv[8] = {xa.x,xa.y,xa.z,xa.w,xb.x,xb.y,xb.z,xb.w};
            float2 wr = *(const float2*)&s_wi[k][j0];
            float2 wz = *(const float2*)&s_wi[k][64 + j0];
            float2 wn = *(const float2*)&s_wi[k][128 + j0];
            #pragma unroll
            for (int nn = 0; nn < 8; ++nn) {
                ar[0][nn] += wr.x*xv[nn]; ar[1][nn] += wr.y*xv[nn];
                az[0][nn] += wz.x*xv[nn]; az[1][nn] += wz.y*xv[nn];
                ani[0][nn]+= wn.x*xv[nn]; ani[1][nn]+= wn.y*xv[nn];
            }
        }
        for (int k = 0; k < 64; ++k) {
            float4 ha = *(const float4*)&s_h[k][n0];
            float4 hb = *(const float4*)&s_h[k][n0 + 4];
            float hv[8] = {ha.x,ha.y,ha.z,ha.w,hb.x,hb.y,hb.z,hb.w};
            float2 wr = *(const float2*)&s_wh[k][j0];
            float2 wz = *(const float2*)&s_wh[k][64 + j0];
            float2 wn = *(const float2*)&s_wh[k][128 + j0];
            #pragma unroll
            for (int nn = 0; nn < 8; ++nn) {
                ar[0][nn] += wr.x*hv[nn]; ar[1][nn] += wr.y*hv[nn];
                az[0][nn] += wz.x*hv[nn]; az[1][nn] += wz.y*hv[nn];
                anh[0][nn]+= wn.x*hv[nn]; anh[1][nn]+= wn.y*hv[nn];
            }
        }

        #pragma unroll
        for (int jj = 0; jj < 2; ++jj) {
            int j = j0 + jj;
            float br  = s_bi[j]      + s_bh[j];
            float bz  = s_bi[64 + j] + s_bh[64 + j];
            float bin = s_bi[128 + j], bhn = s_bh[128 + j];
            #pragma unroll
            for (int nn = 0; nn < 8; ++nn) {
                float r = 1.0f / (1.0f + expf(-(ar[jj][nn] + br)));
                float z = 1.0f / (1.0f + expf(-(az[jj][nn] + bz)));
                float g = tanhf(ani[jj][nn] + bin + r * (anh[jj][nn] + bhn));
                hreg[jj][nn] = (1.0f - z) * g + z * hreg[jj][nn];
            }
        }
        __syncthreads();   // all reads of s_x / old s_h done

        if (t < 3) {
            #pragma unroll
            for (int jj = 0; jj < 2; ++jj) {
                *(float4*)&s_h[j0+jj][n0]     = make_float4(hreg[jj][0],hreg[jj][1],hreg[jj][2],hreg[jj][3]);
                *(float4*)&s_h[j0+jj][n0 + 4] = make_float4(hreg[jj][4],hreg[jj][5],hreg[jj][6],hreg[jj][7]);
            }
            #pragma unroll
            for (int r = 0; r < 11; ++r) {
                int i = tid + r * 512;
                if (i < 5248) { int nl = i / 41, k = i - nl * 41; s_x[k][nl] = xr[r]; }
            }
            __syncthreads();
        }
    }

    #pragma unroll
    for (int jj = 0; jj < 2; ++jj)
        #pragma unroll
        for (int nn = 0; nn < 8; ++nn) {
            int node = nblk + n0 + nn;
            if (node < nnodes) feats[node * 104 + 40 + j0 + jj] = hreg[jj][nn];
        }
}

__global__ __launch_bounds__(256) void k_hw(
    const float* __restrict__ feats,   // [N][104]
    const float* __restrict__ w1,      // [104][40]
    const float* __restrict__ w2,      // [104][40]
    const float* __restrict__ dinv1,
    const float* __restrict__ dinv2,
    float* __restrict__ hs1,           // [N][40]
    float* __restrict__ hs2,
    int nnodes)
{
    __shared__ __align__(16) float s_f[128][108];
    __shared__ __align__(16) float s_w[80][108];
    __shared__ float s_d[2][128];

    const int tid  = threadIdx.x;
    const int nblk = blockIdx.x * 128;

    for (int i = tid; i < 128 * 104; i += 256) {
        int n = i / 104, k = i - n * 104;
        int node = nblk + n; if (node >= nnodes) node = nnodes - 1;
        s_f[n][k] = feats[node * 104 + k];
    }
    for (int i = tid; i < 80 * 104; i += 256) {
        int o = i / 104, k = i - o * 104;
        s_w[o][k] = (o < 40) ? w1[k * 40 + o] : w2[k * 40 + (o - 40)];
    }
    if (tid < 128) {
        int node = nblk + tid; if (node >= nnodes) node = nnodes - 1;
        s_d[0][tid] = dinv1[node]; s_d[1][tid] = dinv2[node];
    }
    __syncthreads();

    const int og = tid & 7, ngp = tid >> 3;   // tile: 4 nodes x 10 outputs
    const int o0 = 10 * og, n0 = 4 * ngp;
    float acc[4][10];
    #pragma unroll
    for (int a = 0; a < 4; ++a)
        #pragma unroll
        for (int b = 0; b < 10; ++b) acc[a][b] = 0.0f;

    for (int k4 = 0; k4 < 104; k4 += 4) {
        float4 f[4];
        #pragma unroll
        for (int nn = 0; nn < 4; ++nn) f[nn] = *(const float4*)&s_f[n0 + nn][k4];
        #pragma unroll
        for (int oo = 0; oo < 10; ++oo) {
            float4 w4 = *(const float4*)&s_w[o0 + oo][k4];
            #pragma unroll
            for (int nn = 0; nn < 4; ++nn)
                acc[nn][oo] += w4.x * f[nn].x + w4.y * f[nn].y + w4.z * f[nn].z + w4.w * f[nn].w;
        }
    }
    #pragma unroll
    for (int nn = 0; nn < 4; ++nn) {
        int node = nblk + n0 + nn;
        if (node >= nnodes) continue;
        #pragma unroll
        for (int oo = 0; oo < 10; ++oo) {
            int o = o0 + oo;
            if (o < 40) hs1[node * 40 + o]        = s_d[0][n0 + nn] * acc[nn][oo];
            else        hs2[node * 40 + (o - 40)] = s_d[1][n0 + nn] * acc[nn][oo];
        }
    }
}

__global__ void k_zero2(int* a, int* b, int n) {
    int i = blockIdx.x * 256 + threadIdx.x;
    if (i < n) { a[i] = 0; b[i] = 0; }
}

__global__ void k_deg(const int* __restrict__ d1, const int* __restrict__ d2,
                      int* c1, int* c2, int E) {
    int i = blockIdx.x * 256 + threadIdx.x;
    if (i < E) { atomicAdd(&c1[d1[i]], 1); atomicAdd(&c2[d2[i]], 1); }
}

__global__ __launch_bounds__(1024) void k_scan(
    const int* __restrict__ cnt, int* __restrict__ roff, int* __restrict__ cur,
    float* __restrict__ dinv, int n)
{
    __shared__ int sp[1024];
    int t = threadIdx.x;
    int C = (n + 1023) >> 10;
    int i0 = t * C, i1 = min(i0 + C, n);
    int s = 0;
    for (int i = i0; i < i1; ++i) s += cnt[i];
    sp[t] = s;
    __syncthreads();
    for (int off = 1; off < 1024; off <<= 1) {
        int v = (t >= off) ? sp[t - off] : 0;
        __syncthreads();
        sp[t] += v;
        __syncthreads();
    }
    int run = sp[t] - s;
    for (int i = i0; i < i1; ++i) {
        int c = cnt[i];
        roff[i] = run; cur[i] = run;
        dinv[i] = rsqrtf((float)(c + 1));
        run += c;
    }
    if (t == 1023) roff[n] = sp[1023];
}

__global__ void k_scatter(const int* __restrict__ e1, const int* __restrict__ e2,
                          int* cur1, int* cur2, int* csr1, int* csr2, int E) {
    int i = blockIdx.x * 256 + threadIdx.x;
    if (i < E) {
        int s = e1[i], d = e1[E + i];
        csr1[atomicAdd(&cur1[d], 1)] = s;
        s = e2[i]; d = e2[E + i];
        csr2[atomicAdd(&cur2[d], 1)] = s;
    }
}

__global__ __launch_bounds__(256) void k_agg(
    const float* __restrict__ hs, const int* __restrict__ csr,
    const int* __restrict__ roff, const float* __restrict__ dinv,
    const float* __restrict__ bias, const float* __restrict__ mw,
    const float* __restrict__ mlp_b, float* __restrict__ out,
    int n, int accumulate)
{
    int wv = threadIdx.x >> 6, lane = threadIdx.x & 63;
    int d = blockIdx.x * 4 + wv;
    if (d >= n) return;
    int beg = roff[d], end = roff[d + 1];
    int fc = lane < 40 ? lane : 0;
    float acc = 0.0f;
    int snext = (beg < end) ? csr[beg] : 0;
    for (int e = beg; e < end; ++e) {
        int s = snext;
        if (e + 1 < end) snext = csr[e + 1];
        acc += hs[s * 40 + fc];
    }
    float v = dinv[d] * (hs[d * 40 + fc] + acc) + bias[fc];
    v = fmaxf(v, 0.0f) * mw[fc];
    if (lane >= 40) v = 0.0f;
    #pragma unroll
    for (int off = 32; off > 0; off >>= 1) v += __shfl_down(v, off);
    if (lane == 0)
        out[d] = accumulate ? (out[d] + v) : (mlp_b[0] + v);
}

extern "C" void kernel_launch(void* const* d_in, const int* in_sizes, int n_in,
                              void* d_out, int out_size, void* d_ws, size_t ws_size,
                              hipStream_t stream)
{
    const float* x      = (const float*)d_in[0];
    const int*   ei1    = (const int*)d_in[1];
    const int*   ei2    = (const int*)d_in[2];
    const float* conv_w = (const float*)d_in[3];
    const float* conv_b = (const float*)d_in[4];
    const float* lin_w  = (const float*)d_in[5];
    const float* lin_b  = (const float*)d_in[6];
    const float* w_ih   = (const float*)d_in[7];
    const float* w_hh   = (const float*)d_in[8];
    const float* b_ih   = (const float*)d_in[9];
    const float* b_hh   = (const float*)d_in[10];
    const float* g1w    = (const float*)d_in[11];
    const float* g1b    = (const float*)d_in[12];
    const float* g2w    = (const float*)d_in[13];
    const float* g2b    = (const float*)d_in[14];
    const float* mw     = (const float*)d_in[15];
    const float* mb     = (const float*)d_in[16];

    const int N = in_sizes[0] / (5 * 395);
    const int E = in_sizes[1] / 2;
    const int R = N * 5;
    float* out = (float*)d_out;

    char* wp = (char*)d_ws;
    auto alloc = [&](size_t bytes) {
        char* p = wp; wp += (bytes + 255) & ~(size_t)255; return p;
    };
    float* seq   = (float*)alloc((size_t)4 * N * 41 * 4);
    float* feats = (float*)alloc((size_t)N * 104 * 4);
    float* hs1   = (float*)alloc((size_t)N * 40 * 4);
    float* hs2   = (float*)alloc((size_t)N * 40 * 4);
    int*   csr1  = (int*)alloc((size_t)E * 4);
    int*   csr2  = (int*)alloc((size_t)E * 4);
    int*   cnt1  = (int*)alloc((size_t)N * 4);
    int*   cnt2  = (int*)alloc((size_t)N * 4);
    int*   roff1 = (int*)alloc((size_t)(N + 1) * 4);
    int*   roff2 = (int*)alloc((size_t)(N + 1) * 4);
    int*   cur1  = (int*)alloc((size_t)N * 4);
    int*   cur2  = (int*)alloc((size_t)N * 4);
    float* dinv1 = (float*)alloc((size_t)N * 4);
    float* dinv2 = (float*)alloc((size_t)N * 4);
    if ((size_t)(wp - (char*)d_ws) > ws_size) return;  // workspace too small

    hipLaunchKernelGGL(k_zero2,  dim3((N + 255) / 256), dim3(256), 0, stream, cnt1, cnt2, N);
    hipLaunchKernelGGL(k_deg,    dim3((E + 255) / 256), dim3(256), 0, stream, ei1 + E, ei2 + E, cnt1, cnt2, E);
    hipLaunchKernelGGL(k_scan,   dim3(1), dim3(1024), 0, stream, cnt1, roff1, cur1, dinv1, N);
    hipLaunchKernelGGL(k_scan,   dim3(1), dim3(1024), 0, stream, cnt2, roff2, cur2, dinv2, N);
    hipLaunchKernelGGL(k_scatter,dim3((E + 255) / 256), dim3(256), 0, stream, ei1, ei2, cur1, cur2, csr1, csr2, E);
    hipLaunchKernelGGL(k_cnn,    dim3((R + 63) / 64), dim3(512), 0, stream, x, conv_w, conv_b, lin_w, lin_b, seq, feats, R, N);
    hipLaunchKernelGGL(k_gru,    dim3((N + 127) / 128), dim3(512), 0, stream, seq, w_ih, w_hh, b_ih, b_hh, feats, N);
    hipLaunchKernelGGL(k_hw,     dim3((N + 127) / 128), dim3(256), 0, stream, feats, g1w, g2w, dinv1, dinv2, hs1, hs2, N);
    hipLaunchKernelGGL(k_agg,    dim3((N + 3) / 4), dim3(256), 0, stream, hs1, csr1, roff1, dinv1, g1b, mw,      mb, out, N, 0);
    hipLaunchKernelGGL(k_agg,    dim3((N + 3) / 4), dim3(256), 0, stream, hs2, csr2, roff2, dinv2, g2b, mw + 40, mb, out, N, 1);
}

// Round 6
// 1129.132 us; speedup vs baseline: 1.4514x; 1.0858x over previous
//
#include <hip/hip_runtime.h>
#include <math.h>

// ---------------------------------------------------------------------------
// Pipeline:
//  k_zero2      : zero degree counters
//  k_deg        : in-degree count per dst (both graphs), int atomics
//  k_scan       : single-block exclusive scan -> CSR row offsets, cursors, dinv
//  k_bcur       : per-bucket cursors = roff[bucket_lo]
//  k_part  (x2) : bucket edges by dst/npb into exact CSR-window regions
//                 (LDS histogram -> one global reservation per bucket per block)
//  k_scatter2(x2): bucket-grouped pairs -> csr (writes confined to ~100KB window)
//  k_cnn        : conv1d(16,k40,s88)+relu + linear 80->40+relu -> seq/feats
//  k_gru        : 128-node blocks, 512 thr, weights+h in LDS, x-prefetch
//  k_hw         : hs_g[n] = dinv_g[n] * (feats[n] @ Wg) for both GCNs
//  k_agg   (x2) : pull aggregation over CSR + bias + relu + fused MLP dot
// ---------------------------------------------------------------------------

#define NB 64   // buckets for dst-locality in CSR build

__global__ __launch_bounds__(512) void k_cnn(
    const float* __restrict__ x,       // [R][395]
    const float* __restrict__ conv_w,  // [16][40]
    const float* __restrict__ conv_b,  // [16]
    const float* __restrict__ lin_w,   // [40][80]
    const float* __restrict__ lin_b,   // [40]
    float* __restrict__ seq,           // [4][N][41]
    float* __restrict__ feats,         // [N][104]
    int nrows, int nnodes)
{
    __shared__ __align__(16) float smem[64 * 200];   // 51.2 KB (sig, then c)
    __shared__ __align__(16) float s_cw[16][44];
    __shared__ __align__(16) float s_lw[40][84];
    __shared__ float s_cb[16];
    __shared__ float s_lb[40];

    const int tid = threadIdx.x;
    const int r0  = blockIdx.x * 64;

    float sg[25];
    #pragma unroll
    for (int it = 0; it < 25; ++it) {
        int i = tid + it * 512;
        int row = i / 200, e = i - row * 200;
        int p = e / 40, kk = e - p * 40;
        int gr = r0 + row; if (gr >= nrows) gr = nrows - 1;
        sg[it] = x[(size_t)gr * 395 + 3 + 88 * p + kk];
    }

    for (int i = tid; i < 640;  i += 512) s_cw[i / 40][i % 40] = conv_w[i];
    for (int i = tid; i < 3200; i += 512) s_lw[i / 80][i % 80] = lin_w[i];
    if (tid < 16) s_cb[tid] = conv_b[tid];
    if (tid >= 64 && tid < 104) s_lb[tid - 64] = lin_b[tid - 64];

    if (tid < 64) {
        int gr = r0 + tid;
        if (gr < nrows) {
            float y = x[(size_t)gr * 395 + 2];
            int node = gr / 5, t = gr - node * 5;
            if (t < 4) seq[(t * nnodes + node) * 41 + 40] = y;
        }
    }

    #pragma unroll
    for (int it = 0; it < 25; ++it) {
        int i = tid + it * 512;
        int row = i / 200, e = i - row * 200;
        smem[row * 200 + e] = sg[it];
    }
    __syncthreads();

    const int row = tid >> 3, cg = tid & 7;
    float creg[2][5];
    {
        float acc[2][5];
        #pragma unroll
        for (int cc = 0; cc < 2; ++cc) {
            float b = s_cb[2 * cg + cc];
            #pragma unroll
            for (int p = 0; p < 5; ++p) acc[cc][p] = b;
        }
        #pragma unroll
        for (int k4 = 0; k4 < 40; k4 += 4) {
            float4 sv[5];
            #pragma unroll
            for (int p = 0; p < 5; ++p)
                sv[p] = *(const float4*)&smem[row * 200 + p * 40 + k4];
            #pragma unroll
            for (int cc = 0; cc < 2; ++cc) {
                float4 w4 = *(const float4*)&s_cw[2 * cg + cc][k4];
                #pragma unroll
                for (int p = 0; p < 5; ++p)
                    acc[cc][p] += w4.x * sv[p].x + w4.y * sv[p].y + w4.z * sv[p].z + w4.w * sv[p].w;
            }
        }
        #pragma unroll
        for (int cc = 0; cc < 2; ++cc)
            #pragma unroll
            for (int p = 0; p < 5; ++p) creg[cc][p] = fmaxf(acc[cc][p], 0.0f);
    }
    __syncthreads();

    #pragma unroll
    for (int cc = 0; cc < 2; ++cc)
        #pragma unroll
        for (int p = 0; p < 5; ++p)
            smem[row * 84 + (2 * cg + cc) * 5 + p] = creg[cc][p];
    __syncthreads();

    {
        const int jg = tid & 7;
        float acc[5];
        #pragma unroll
        for (int jj = 0; jj < 5; ++jj) acc[jj] = s_lb[5 * jg + jj];
        #pragma unroll
        for (int i4 = 0; i4 < 80; i4 += 4) {
            float4 c0 = *(const float4*)&smem[row * 84 + i4];
            #pragma unroll
            for (int jj = 0; jj < 5; ++jj) {
                float4 w4 = *(const float4*)&s_lw[5 * jg + jj][i4];
                acc[jj] += w4.x * c0.x + w4.y * c0.y + w4.z * c0.z + w4.w * c0.w;
            }
        }
        int gr = r0 + row;
        if (gr < nrows) {
            int node = gr / 5, t = gr - node * 5;
            #pragma unroll
            for (int jj = 0; jj < 5; ++jj) {
                float v = fmaxf(acc[jj], 0.0f);
                if (t < 4) seq[(t * nnodes + node) * 41 + 5 * jg + jj] = v;
                else       feats[node * 104 + 5 * jg + jj] = v;
            }
        }
    }
}

__global__ __launch_bounds__(512) void k_gru(
    const float* __restrict__ seq,    // [4][N][41]
    const float* __restrict__ w_ih,   // [192][41]
    const float* __restrict__ w_hh,   // [192][64]
    const float* __restrict__ b_ih,
    const float* __restrict__ b_hh,
    float* __restrict__ feats,        // [N][104]
    int nnodes)
{
    __shared__ __align__(16) float s_wi[41][192];
    __shared__ __align__(16) float s_wh[64][192];
    __shared__ __align__(16) float s_h[64][132];
    __shared__ __align__(16) float s_x[41][132];
    __shared__ float s_bi[192], s_bh[192];

    const int tid  = threadIdx.x;
    const int nblk = blockIdx.x * 128;

    float xr[11];
    #pragma unroll
    for (int r = 0; r < 11; ++r) {
        int i = tid + r * 512;
        if (i < 5248) {
            int nl = i / 41, k = i - nl * 41;
            int node = nblk + nl; if (node >= nnodes) node = nnodes - 1;
            xr[r] = seq[(size_t)(0 * nnodes + node) * 41 + k];
        }
    }

    for (int i = tid; i < 192 * 41; i += 512) { int g = i / 41, k = i - g * 41; s_wi[k][g] = w_ih[i]; }
    for (int i = tid; i < 192 * 64; i += 512) { int g = i >> 6,  k = i & 63;    s_wh[k][g] = w_hh[i]; }
    if (tid < 192) { s_bi[tid] = b_ih[tid]; s_bh[tid] = b_hh[tid]; }
    for (int i = tid; i < 64 * 132; i += 512) ((float*)s_h)[i] = 0.0f;

    #pragma unroll
    for (int r = 0; r < 11; ++r) {
        int i = tid + r * 512;
        if (i < 5248) { int nl = i / 41, k = i - nl * 41; s_x[k][nl] = xr[r]; }
    }
    __syncthreads();

    const int jg = tid & 31, ngp = tid >> 5;
    const int j0 = 2 * jg, n0 = 8 * ngp;

    float hreg[2][8];
    #pragma unroll
    for (int a = 0; a < 2; ++a)
        #pragma unroll
        for (int b = 0; b < 8; ++b) hreg[a][b] = 0.0f;

    for (int t = 0; t < 4; ++t) {
        if (t < 3) {
            #pragma unroll
            for (int r = 0; r < 11; ++r) {
                int i = tid + r * 512;
                if (i < 5248) {
                    int nl = i / 41, k = i - nl * 41;
                    int node = nblk + nl; if (node >= nnodes) node = nnodes - 1;
                    xr[r] = seq[(size_t)((t + 1) * nnodes + node) * 41 + k];
                }
            }
        }

        float ar[2][8], az[2][8], ani[2][8], anh[2][8];
        #pragma unroll
        for (int a = 0; a < 2; ++a)
            #pragma unroll
            for (int b = 0; b < 8; ++b) { ar[a][b]=0.f; az[a][b]=0.f; ani[a][b]=0.f; anh[a][b]=0.f; }

        for (int k = 0; k < 41; ++k) {
            float4 xa = *(const float4*)&s_x[k][n0];
            float4 xb = *(const float4*)&s_x[k][n0 + 4];
            float xv[8] = {xa.x,xa.y,xa.z,xa.w,xb.x,xb.y,xb.z,xb.w};
            float2 wr = *(const float2*)&s_wi[k][j0];
            float2 wz = *(const float2*)&s_wi[k][64 + j0];
            float2 wn = *(const float2*)&s_wi[k][128 + j0];
            #pragma unroll
            for (int nn = 0; nn < 8; ++nn) {
                ar[0][nn] += wr.x*xv[nn]; ar[1][nn] += wr.y*xv[nn];
                az[0][nn] += wz.x*xv[nn]; az[1][nn] += wz.y*xv[nn];
                ani[0][nn]+= wn.x*xv[nn]; ani[1][nn]+= wn.y*xv[nn];
            }
        }
        for (int k = 0; k < 64; ++k) {
            float4 ha = *(const float4*)&s_h[k][n0];
            float4 hb = *(const float4*)&s_h[k][n0 + 4];
            float hv[8] = {ha.x,ha.y,ha.z,ha.w,hb.x,hb.y,hb.z,hb.w};
            float2 wr = *(const float2*)&s_wh[k][j0];
            float2 wz = *(const float2*)&s_wh[k][64 + j0];
            float2 wn = *(const float2*)&s_wh[k][128 + j0];
            #pragma unroll
            for (int nn = 0; nn < 8; ++nn) {
                ar[0][nn] += wr.x*hv[nn]; ar[1][nn] += wr.y*hv[nn];
                az[0][nn] += wz.x*hv[nn]; az[1][nn] += wz.y*hv[nn];
                anh[0][nn]+= wn.x*hv[nn]; anh[1][nn]+= wn.y*hv[nn];
            }
        }

        #pragma unroll
        for (int jj = 0; jj < 2; ++jj) {
            int j = j0 + jj;
            float br  = s_bi[j]      + s_bh[j];
            float bz  = s_bi[64 + j] + s_bh[64 + j];
            float bin = s_bi[128 + j], bhn = s_bh[128 + j];
            #pragma unroll
            for (int nn = 0; nn < 8; ++nn) {
                float r = 1.0f / (1.0f + expf(-(ar[jj][nn] + br)));
                float z = 1.0f / (1.0f + expf(-(az[jj][nn] + bz)));
                float g = tanhf(ani[jj][nn] + bin + r * (anh[jj][nn] + bhn));
                hreg[jj][nn] = (1.0f - z) * g + z * hreg[jj][nn];
            }
        }
        __syncthreads();

        if (t < 3) {
            #pragma unroll
            for (int jj = 0; jj < 2; ++jj) {
                *(float4*)&s_h[j0+jj][n0]     = make_float4(hreg[jj][0],hreg[jj][1],hreg[jj][2],hreg[jj][3]);
                *(float4*)&s_h[j0+jj][n0 + 4] = make_float4(hreg[jj][4],hreg[jj][5],hreg[jj][6],hreg[jj][7]);
            }
            #pragma unroll
            for (int r = 0; r < 11; ++r) {
                int i = tid + r * 512;
                if (i < 5248) { int nl = i / 41, k = i - nl * 41; s_x[k][nl] = xr[r]; }
            }
            __syncthreads();
        }
    }

    #pragma unroll
    for (int jj = 0; jj < 2; ++jj)
        #pragma unroll
        for (int nn = 0; nn < 8; ++nn) {
            int node = nblk + n0 + nn;
            if (node < nnodes) feats[node * 104 + 40 + j0 + jj] = hreg[jj][nn];
        }
}

__global__ __launch_bounds__(256) void k_hw(
    const float* __restrict__ feats,   // [N][104]
    const float* __restrict__ w1,      // [104][40]
    const float* __restrict__ w2,      // [104][40]
    const float* __restrict__ dinv1,
    const float* __restrict__ dinv2,
    float* __restrict__ hs1,           // [N][40]
    float* __restrict__ hs2,
    int nnodes)
{
    __shared__ __align__(16) float s_f[128][108];
    __shared__ __align__(16) float s_w[80][108];
    __shared__ float s_d[2][128];

    const int tid  = threadIdx.x;
    const int nblk = blockIdx.x * 128;

    for (int i = tid; i < 128 * 104; i += 256) {
        int n = i / 104, k = i - n * 104;
        int node = nblk + n; if (node >= nnodes) node = nnodes - 1;
        s_f[n][k] = feats[node * 104 + k];
    }
    for (int i = tid; i < 80 * 104; i += 256) {
        int o = i / 104, k = i - o * 104;
        s_w[o][k] = (o < 40) ? w1[k * 40 + o] : w2[k * 40 + (o - 40)];
    }
    if (tid < 128) {
        int node = nblk + tid; if (node >= nnodes) node = nnodes - 1;
        s_d[0][tid] = dinv1[node]; s_d[1][tid] = dinv2[node];
    }
    __syncthreads();

    const int og = tid & 7, ngp = tid >> 3;
    const int o0 = 10 * og, n0 = 4 * ngp;
    float acc[4][10];
    #pragma unroll
    for (int a = 0; a < 4; ++a)
        #pragma unroll
        for (int b = 0; b < 10; ++b) acc[a][b] = 0.0f;

    for (int k4 = 0; k4 < 104; k4 += 4) {
        float4 f[4];
        #pragma unroll
        for (int nn = 0; nn < 4; ++nn) f[nn] = *(const float4*)&s_f[n0 + nn][k4];
        #pragma unroll
        for (int oo = 0; oo < 10; ++oo) {
            float4 w4 = *(const float4*)&s_w[o0 + oo][k4];
            #pragma unroll
            for (int nn = 0; nn < 4; ++nn)
                acc[nn][oo] += w4.x * f[nn].x + w4.y * f[nn].y + w4.z * f[nn].z + w4.w * f[nn].w;
        }
    }
    #pragma unroll
    for (int nn = 0; nn < 4; ++nn) {
        int node = nblk + n0 + nn;
        if (node >= nnodes) continue;
        #pragma unroll
        for (int oo = 0; oo < 10; ++oo) {
            int o = o0 + oo;
            if (o < 40) hs1[node * 40 + o]        = s_d[0][n0 + nn] * acc[nn][oo];
            else        hs2[node * 40 + (o - 40)] = s_d[1][n0 + nn] * acc[nn][oo];
        }
    }
}

__global__ void k_zero2(int* a, int* b, int n) {
    int i = blockIdx.x * 256 + threadIdx.x;
    if (i < n) { a[i] = 0; b[i] = 0; }
}

__global__ void k_deg(const int* __restrict__ d1, const int* __restrict__ d2,
                      int* c1, int* c2, int E) {
    int i = blockIdx.x * 256 + threadIdx.x;
    if (i < E) { atomicAdd(&c1[d1[i]], 1); atomicAdd(&c2[d2[i]], 1); }
}

__global__ __launch_bounds__(1024) void k_scan(
    const int* __restrict__ cnt, int* __restrict__ roff, int* __restrict__ cur,
    float* __restrict__ dinv, int n)
{
    __shared__ int sp[1024];
    int t = threadIdx.x;
    int C = (n + 1023) >> 10;
    int i0 = t * C, i1 = min(i0 + C, n);
    int s = 0;
    for (int i = i0; i < i1; ++i) s += cnt[i];
    sp[t] = s;
    __syncthreads();
    for (int off = 1; off < 1024; off <<= 1) {
        int v = (t >= off) ? sp[t - off] : 0;
        __syncthreads();
        sp[t] += v;
        __syncthreads();
    }
    int run = sp[t] - s;
    for (int i = i0; i < i1; ++i) {
        int c = cnt[i];
        roff[i] = run; cur[i] = run;
        dinv[i] = rsqrtf((float)(c + 1));
        run += c;
    }
    if (t == 1023) roff[n] = sp[1023];
}

// per-bucket cursors = CSR offset of the bucket's first node
__global__ void k_bcur(const int* __restrict__ roff1, const int* __restrict__ roff2,
                       int* __restrict__ bcur, int npb, int n) {
    int b = threadIdx.x;
    if (b < NB) {
        int lo = min(b * npb, n);
        bcur[b]      = roff1[lo];
        bcur[NB + b] = roff2[lo];
    }
}

// bucket edges by dst/npb into exact per-bucket CSR-window regions of pairs[]
__global__ __launch_bounds__(256) void k_part(
    const int* __restrict__ e,          // [2][E]: src then dst
    int* __restrict__ bcur,             // NB cursors (this graph's slice)
    unsigned long long* __restrict__ pairs,
    int E, int npb)
{
    __shared__ int s_cnt[NB];
    __shared__ int s_base[NB];
    const int tid = threadIdx.x;
    const int i0  = blockIdx.x * 1024 + tid;

    if (tid < NB) s_cnt[tid] = 0;
    __syncthreads();

    int sv[4], dv[4], bv[4], rv[4];
    #pragma unroll
    for (int k = 0; k < 4; ++k) {
        int i = i0 + k * 256;
        if (i < E) {
            sv[k] = e[i]; dv[k] = e[E + i];
            bv[k] = dv[k] / npb;
            rv[k] = atomicAdd(&s_cnt[bv[k]], 1);
        }
    }
    __syncthreads();
    if (tid < NB && s_cnt[tid] > 0) s_base[tid] = atomicAdd(&bcur[tid], s_cnt[tid]);
    __syncthreads();
    #pragma unroll
    for (int k = 0; k < 4; ++k) {
        int i = i0 + k * 256;
        if (i < E)
            pairs[s_base[bv[k]] + rv[k]] =
                ((unsigned long long)(unsigned)dv[k] << 32) | (unsigned)sv[k];
    }
}

// bucket-grouped pairs -> csr: writes confined to ~E/NB window => L2-friendly
__global__ void k_scatter2(const unsigned long long* __restrict__ pairs,
                           int* __restrict__ cur, int* __restrict__ csr, int E) {
    int i = blockIdx.x * 256 + threadIdx.x;
    if (i < E) {
        unsigned long long p = pairs[i];
        int d = (int)(p >> 32), s = (int)(p & 0xffffffffu);
        csr[atomicAdd(&cur[d], 1)] = s;
    }
}

__global__ __launch_bounds__(256) void k_agg(
    const float* __restrict__ hs, const int* __restrict__ csr,
    const int* __restrict__ roff, const float* __restrict__ dinv,
    const float* __restrict__ bias, const float* __restrict__ mw,
    const float* __restrict__ mlp_b, float* __restrict__ out,
    int n, int accumulate)
{
    int wv = threadIdx.x >> 6, lane = threadIdx.x & 63;
    int d = blockIdx.x * 4 + wv;
    if (d >= n) return;
    int beg = roff[d], end = roff[d + 1];
    int fc = lane < 40 ? lane : 0;
    float acc = 0.0f;
    int snext = (beg < end) ? csr[beg] : 0;
    for (int e = beg; e < end; ++e) {
        int s = snext;
        if (e + 1 < end) snext = csr[e + 1];
        acc += hs[s * 40 + fc];
    }
    float v = dinv[d] * (hs[d * 40 + fc] + acc) + bias[fc];
    v = fmaxf(v, 0.0f) * mw[fc];
    if (lane >= 40) v = 0.0f;
    #pragma unroll
    for (int off = 32; off > 0; off >>= 1) v += __shfl_down(v, off);
    if (lane == 0)
        out[d] = accumulate ? (out[d] + v) : (mlp_b[0] + v);
}

extern "C" void kernel_launch(void* const* d_in, const int* in_sizes, int n_in,
                              void* d_out, int out_size, void* d_ws, size_t ws_size,
                              hipStream_t stream)
{
    const float* x      = (const float*)d_in[0];
    const int*   ei1    = (const int*)d_in[1];
    const int*   ei2    = (const int*)d_in[2];
    const float* conv_w = (const float*)d_in[3];
    const float* conv_b = (const float*)d_in[4];
    const float* lin_w  = (const float*)d_in[5];
    const float* lin_b  = (const float*)d_in[6];
    const float* w_ih   = (const float*)d_in[7];
    const float* w_hh   = (const float*)d_in[8];
    const float* b_ih   = (const float*)d_in[9];
    const float* b_hh   = (const float*)d_in[10];
    const float* g1w    = (const float*)d_in[11];
    const float* g1b    = (const float*)d_in[12];
    const float* g2w    = (const float*)d_in[13];
    const float* g2b    = (const float*)d_in[14];
    const float* mw     = (const float*)d_in[15];
    const float* mb     = (const float*)d_in[16];

    const int N = in_sizes[0] / (5 * 395);
    const int E = in_sizes[1] / 2;
    const int R = N * 5;
    float* out = (float*)d_out;

    char* wp = (char*)d_ws;
    auto alloc = [&](size_t bytes) {
        char* p = wp; wp += (bytes + 255) & ~(size_t)255; return p;
    };
    size_t seq_bytes = (size_t)4 * N * 41 * 4;
    float* seq   = (float*)alloc(seq_bytes);
    float* feats = (float*)alloc((size_t)N * 104 * 4);
    float* hs1   = (float*)alloc((size_t)N * 40 * 4);
    float* hs2   = (float*)alloc((size_t)N * 40 * 4);
    int*   csr1  = (int*)alloc((size_t)E * 4);
    int*   csr2  = (int*)alloc((size_t)E * 4);
    int*   cnt1  = (int*)alloc((size_t)N * 4);
    int*   cnt2  = (int*)alloc((size_t)N * 4);
    int*   roff1 = (int*)alloc((size_t)(N + 1) * 4);
    int*   roff2 = (int*)alloc((size_t)(N + 1) * 4);
    int*   cur1  = (int*)alloc((size_t)N * 4);
    int*   cur2  = (int*)alloc((size_t)N * 4);
    float* dinv1 = (float*)alloc((size_t)N * 4);
    float* dinv2 = (float*)alloc((size_t)N * 4);
    int*   bcur  = (int*)alloc((size_t)2 * NB * 4);

    // pairs buffers alias the (not-yet-written) seq region when they fit:
    // all CSR-build kernels complete on-stream before k_cnn writes seq.
    unsigned long long *pairs1, *pairs2;
    if (2 * (size_t)E * 8 <= seq_bytes) {
        pairs1 = (unsigned long long*)seq;
        pairs2 = pairs1 + E;
    } else {
        pairs1 = (unsigned long long*)alloc((size_t)E * 8);
        pairs2 = (unsigned long long*)alloc((size_t)E * 8);
    }
    if ((size_t)(wp - (char*)d_ws) > ws_size) return;  // workspace too small

    const int npb = (N + NB - 1) / NB;

    hipLaunchKernelGGL(k_zero2,    dim3((N + 255) / 256), dim3(256), 0, stream, cnt1, cnt2, N);
    hipLaunchKernelGGL(k_deg,      dim3((E + 255) / 256), dim3(256), 0, stream, ei1 + E, ei2 + E, cnt1, cnt2, E);
    hipLaunchKernelGGL(k_scan,     dim3(1), dim3(1024), 0, stream, cnt1, roff1, cur1, dinv1, N);
    hipLaunchKernelGGL(k_scan,     dim3(1), dim3(1024), 0, stream, cnt2, roff2, cur2, dinv2, N);
    hipLaunchKernelGGL(k_bcur,     dim3(1), dim3(NB), 0, stream, roff1, roff2, bcur, npb, N);
    hipLaunchKernelGGL(k_part,     dim3((E + 1023) / 1024), dim3(256), 0, stream, ei1, bcur,      pairs1, E, npb);
    hipLaunchKernelGGL(k_part,     dim3((E + 1023) / 1024), dim3(256), 0, stream, ei2, bcur + NB, pairs2, E, npb);
    hipLaunchKernelGGL(k_scatter2, dim3((E + 255) / 256), dim3(256), 0, stream, pairs1, cur1, csr1, E);
    hipLaunchKernelGGL(k_scatter2, dim3((E + 255) / 256), dim3(256), 0, stream, pairs2, cur2, csr2, E);
    hipLaunchKernelGGL(k_cnn,      dim3((R + 63) / 64), dim3(512), 0, stream, x, conv_w, conv_b, lin_w, lin_b, seq, feats, R, N);
    hipLaunchKernelGGL(k_gru,      dim3((N + 127) / 128), dim3(512), 0, stream, seq, w_ih, w_hh, b_ih, b_hh, feats, N);
    hipLaunchKernelGGL(k_hw,       dim3((N + 127) / 128), dim3(256), 0, stream, feats, g1w, g2w, dinv1, dinv2, hs1, hs2, N);
    hipLaunchKernelGGL(k_agg,      dim3((N + 3) / 4), dim3(256), 0, stream, hs1, csr1, roff1, dinv1, g1b, mw,      mb, out, N, 0);
    hipLaunchKernelGGL(k_agg,      dim3((N + 3) / 4), dim3(256), 0, stream, hs2, csr2, roff2, dinv2, g2b, mw + 40, mb, out, N, 1);
}